// Round 1
// baseline (216.849 us; speedup 1.0000x reference)
//
#include <hip/hip_runtime.h>
#include <math.h>

#define NBLK 2048
#define NTHR 256

// element = -log C_3(kappa) - dot(pred, target)
// exact branch (k<100): -logC = k + log1p(-exp(-2k)) - log(k) + log(2*pi)
// approx branch (k>=100, m=3 => b=0): -logC = sqrt(4+k^2) + offset
//   offset = exact(100) - approx(100) applied so the two branches are continuous:
//   -logC_big = sqrt(4+k^2) - 2.78729112
__device__ __forceinline__ float vmf_elem(float x, float y, float z,
                                          float tx, float ty, float tz) {
    float k2  = x * x + y * y + z * z;
    float dot = x * tx + y * ty + z * tz;
    float k   = sqrtf(k2);
    float e2k = __expf(-2.0f * k);
    float nlc_small = k + log1pf(-e2k) - __logf(k) + 1.8378770664093453f;
    float nlc_big   = sqrtf(4.0f + k2) - 2.78729112f;
    float nlc = (k < 100.0f) ? nlc_small : nlc_big;
    return nlc - dot;
}

__global__ __launch_bounds__(NTHR) void vmf_partial_kernel(
    const float* __restrict__ pred, const float* __restrict__ targ,
    float* __restrict__ partial, int nchunk, int nrem, int nbase) {
    const float4* p4 = reinterpret_cast<const float4*>(pred);
    const float4* t4 = reinterpret_cast<const float4*>(targ);
    int tid    = blockIdx.x * blockDim.x + threadIdx.x;
    int stride = gridDim.x * blockDim.x;

    float acc = 0.0f;
    // Each chunk = 4 rows = 12 floats = 3 aligned float4 loads per operand.
    for (int c = tid; c < nchunk; c += stride) {
        float4 p0 = p4[3 * c + 0], p1 = p4[3 * c + 1], p2 = p4[3 * c + 2];
        float4 t0 = t4[3 * c + 0], t1 = t4[3 * c + 1], t2 = t4[3 * c + 2];
        acc += vmf_elem(p0.x, p0.y, p0.z, t0.x, t0.y, t0.z);
        acc += vmf_elem(p0.w, p1.x, p1.y, t0.w, t1.x, t1.y);
        acc += vmf_elem(p1.z, p1.w, p2.x, t1.z, t1.w, t2.x);
        acc += vmf_elem(p2.y, p2.z, p2.w, t2.y, t2.z, t2.w);
    }
    // Tail rows (N not divisible by 4) handled by global thread 0.
    if (tid == 0) {
        for (int r = 0; r < nrem; ++r) {
            int i = nbase + r;
            acc += vmf_elem(pred[3 * i], pred[3 * i + 1], pred[3 * i + 2],
                            targ[3 * i], targ[3 * i + 1], targ[3 * i + 2]);
        }
    }

    // Wave (64-lane) shuffle reduction, then cross-wave via LDS.
    for (int off = 32; off > 0; off >>= 1)
        acc += __shfl_down(acc, off, 64);
    __shared__ float sdata[NTHR / 64];
    int lane = threadIdx.x & 63, wid = threadIdx.x >> 6;
    if (lane == 0) sdata[wid] = acc;
    __syncthreads();
    if (threadIdx.x == 0) {
        float s = 0.0f;
        #pragma unroll
        for (int w = 0; w < NTHR / 64; ++w) s += sdata[w];
        partial[blockIdx.x] = s;
    }
}

__global__ __launch_bounds__(64) void vmf_final_kernel(
    const float* __restrict__ partial, float* __restrict__ out,
    int nblk, float invN) {
    float s = 0.0f;
    for (int i = threadIdx.x; i < nblk; i += 64) s += partial[i];
    for (int off = 32; off > 0; off >>= 1)
        s += __shfl_down(s, off, 64);
    if (threadIdx.x == 0) out[0] = s * invN;
}

extern "C" void kernel_launch(void* const* d_in, const int* in_sizes, int n_in,
                              void* d_out, int out_size, void* d_ws, size_t ws_size,
                              hipStream_t stream) {
    const float* pred = (const float*)d_in[0];
    const float* targ = (const float*)d_in[1];
    float* out = (float*)d_out;
    float* partial = (float*)d_ws;

    long long nrows = (long long)in_sizes[0] / 3;
    int nchunk = (int)(nrows / 4);
    int nrem   = (int)(nrows % 4);
    int nbase  = nchunk * 4;

    int blocks = (nchunk + NTHR - 1) / NTHR;
    if (blocks > NBLK) blocks = NBLK;
    if (blocks < 1) blocks = 1;

    vmf_partial_kernel<<<blocks, NTHR, 0, stream>>>(pred, targ, partial,
                                                    nchunk, nrem, nbase);
    vmf_final_kernel<<<1, 64, 0, stream>>>(partial, out, blocks,
                                           1.0f / (float)nrows);
}

// Round 2
// 208.395 us; speedup vs baseline: 1.0406x; 1.0406x over previous
//
#include <hip/hip_runtime.h>
#include <math.h>

#define NTHR 256
#define MAXBLK 8192

// element = -log C_3(kappa) - dot(pred, target)
// exact (k<100):  -logC = k + log((1-exp(-2k))/k) + log(2*pi)
//   (folds log1p(-e)-log(k) into one native log; log(2pi)=1.8378770664)
// approx (k>=100, m=3 => b=0) with continuity offset folded in:
//   -logC = sqrt(4+k^2) - 2.78729112
__device__ __forceinline__ float vmf_elem(float x, float y, float z,
                                          float tx, float ty, float tz) {
    float k2  = fmaf(x, x, fmaf(y, y, z * z));
    float dot = fmaf(x, tx, fmaf(y, ty, z * tz));
    float k   = __builtin_amdgcn_sqrtf(k2);
    float e2k = __expf(-2.0f * k);
    float u   = fmaxf(1.0f - e2k, 1e-37f);
    float lr  = __logf(u * __builtin_amdgcn_rcpf(fmaxf(k, 1e-30f)));
    float nlc_small = k + lr + 1.8378770664093453f;
    float nlc_big   = __builtin_amdgcn_sqrtf(4.0f + k2) - 2.78729112f;
    float nlc = (k < 100.0f) ? nlc_small : nlc_big;
    return nlc - dot;
}

// Each chunk = 8 rows = 24 floats = 6 aligned float4 loads per operand.
__global__ __launch_bounds__(NTHR) void vmf_partial_kernel(
    const float* __restrict__ pred, const float* __restrict__ targ,
    float* __restrict__ partial, int nchunk, int nrem, int nbase) {
    const float4* p4 = reinterpret_cast<const float4*>(pred);
    const float4* t4 = reinterpret_cast<const float4*>(targ);
    int tid    = blockIdx.x * blockDim.x + threadIdx.x;
    int stride = gridDim.x * blockDim.x;

    float acc = 0.0f;
    for (int c = tid; c < nchunk; c += stride) {
        int b = 6 * c;
        float4 p0 = p4[b + 0], p1 = p4[b + 1], p2 = p4[b + 2];
        float4 p3 = p4[b + 3], p5 = p4[b + 4], p6 = p4[b + 5];
        float4 t0 = t4[b + 0], t1 = t4[b + 1], t2 = t4[b + 2];
        float4 t3 = t4[b + 3], t5 = t4[b + 4], t6 = t4[b + 5];
        acc += vmf_elem(p0.x, p0.y, p0.z, t0.x, t0.y, t0.z);
        acc += vmf_elem(p0.w, p1.x, p1.y, t0.w, t1.x, t1.y);
        acc += vmf_elem(p1.z, p1.w, p2.x, t1.z, t1.w, t2.x);
        acc += vmf_elem(p2.y, p2.z, p2.w, t2.y, t2.z, t2.w);
        acc += vmf_elem(p3.x, p3.y, p3.z, t3.x, t3.y, t3.z);
        acc += vmf_elem(p3.w, p5.x, p5.y, t3.w, t5.x, t5.y);
        acc += vmf_elem(p5.z, p5.w, p6.x, t5.z, t5.w, t6.x);
        acc += vmf_elem(p6.y, p6.z, p6.w, t6.y, t6.z, t6.w);
    }
    // Tail rows (N not divisible by 8) handled by global thread 0.
    if (tid == 0) {
        for (int r = 0; r < nrem; ++r) {
            int i = nbase + r;
            acc += vmf_elem(pred[3 * i], pred[3 * i + 1], pred[3 * i + 2],
                            targ[3 * i], targ[3 * i + 1], targ[3 * i + 2]);
        }
    }

    // Wave (64-lane) shuffle reduction, then cross-wave via LDS.
    for (int off = 32; off > 0; off >>= 1)
        acc += __shfl_down(acc, off, 64);
    __shared__ float sdata[NTHR / 64];
    int lane = threadIdx.x & 63, wid = threadIdx.x >> 6;
    if (lane == 0) sdata[wid] = acc;
    __syncthreads();
    if (threadIdx.x == 0) {
        float s = 0.0f;
        #pragma unroll
        for (int w = 0; w < NTHR / 64; ++w) s += sdata[w];
        partial[blockIdx.x] = s;
    }
}

__global__ __launch_bounds__(NTHR) void vmf_final_kernel(
    const float* __restrict__ partial, float* __restrict__ out,
    int nblk, float invN) {
    float s = 0.0f;
    for (int i = threadIdx.x; i < nblk; i += NTHR) s += partial[i];
    for (int off = 32; off > 0; off >>= 1)
        s += __shfl_down(s, off, 64);
    __shared__ float sdata[NTHR / 64];
    int lane = threadIdx.x & 63, wid = threadIdx.x >> 6;
    if (lane == 0) sdata[wid] = s;
    __syncthreads();
    if (threadIdx.x == 0) {
        float tot = 0.0f;
        #pragma unroll
        for (int w = 0; w < NTHR / 64; ++w) tot += sdata[w];
        out[0] = tot * invN;
    }
}

extern "C" void kernel_launch(void* const* d_in, const int* in_sizes, int n_in,
                              void* d_out, int out_size, void* d_ws, size_t ws_size,
                              hipStream_t stream) {
    const float* pred = (const float*)d_in[0];
    const float* targ = (const float*)d_in[1];
    float* out = (float*)d_out;
    float* partial = (float*)d_ws;

    long long nrows = (long long)in_sizes[0] / 3;
    int nchunk = (int)(nrows / 8);
    int nrem   = (int)(nrows % 8);
    int nbase  = nchunk * 8;

    int blocks = (nchunk + NTHR - 1) / NTHR;
    if (blocks > MAXBLK) blocks = MAXBLK;
    if (blocks < 1) blocks = 1;

    vmf_partial_kernel<<<blocks, NTHR, 0, stream>>>(pred, targ, partial,
                                                    nchunk, nrem, nbase);
    vmf_final_kernel<<<1, NTHR, 0, stream>>>(partial, out, blocks,
                                             1.0f / (float)nrows);
}

// Round 3
// 205.566 us; speedup vs baseline: 1.0549x; 1.0138x over previous
//
#include <hip/hip_runtime.h>
#include <math.h>

#define NTHR 256
#define MAXBLK 1536
#define TILE_ROWS 1024   // rows per block-iteration
#define TILE_F4   768    // float4s per operand per tile (1024*12B/16B)

// element = -log C_3(kappa) - dot(pred, target)
// exact (k<100):  -logC = k + log((1-exp(-2k))/k) + log(2*pi)
// approx (k>=100, m=3 => b=0) with continuity offset folded in:
//   -logC = sqrt(4+k^2) - 2.78729112
__device__ __forceinline__ float vmf_elem(float x, float y, float z,
                                          float tx, float ty, float tz) {
    float k2  = fmaf(x, x, fmaf(y, y, z * z));
    float dot = fmaf(x, tx, fmaf(y, ty, z * tz));
    float k   = __builtin_amdgcn_sqrtf(k2);
    float e2k = __expf(-2.0f * k);
    float u   = fmaxf(1.0f - e2k, 1e-37f);
    float lr  = __logf(u * __builtin_amdgcn_rcpf(fmaxf(k, 1e-30f)));
    float nlc_small = k + lr + 1.8378770664093453f;
    float nlc_big   = __builtin_amdgcn_sqrtf(4.0f + k2) - 2.78729112f;
    float nlc = (k < 100.0f) ? nlc_small : nlc_big;
    return nlc - dot;
}

__device__ __forceinline__ float vmf_row(const float* r, const float* t) {
    return vmf_elem(r[0], r[1], r[2], t[0], t[1], t[2]);
}

__global__ __launch_bounds__(NTHR) void vmf_partial_kernel(
    const float* __restrict__ pred, const float* __restrict__ targ,
    float* __restrict__ partial, int ntiles, int nrem, long long nbase) {
    __shared__ float4 lp[TILE_F4];
    __shared__ float4 lt[TILE_F4];
    const float4* p4 = reinterpret_cast<const float4*>(pred);
    const float4* t4 = reinterpret_cast<const float4*>(targ);
    const int tid = threadIdx.x;

    float acc = 0.0f;
    for (int tile = blockIdx.x; tile < ntiles; tile += gridDim.x) {
        long long base = (long long)tile * TILE_F4;
        __syncthreads();  // previous iteration's readers done before overwrite
        // Fully coalesced: consecutive lanes -> consecutive float4s.
        lp[tid          ] = p4[base + tid          ];
        lp[tid + NTHR   ] = p4[base + tid + NTHR   ];
        lp[tid + 2*NTHR ] = p4[base + tid + 2*NTHR ];
        lt[tid          ] = t4[base + tid          ];
        lt[tid + NTHR   ] = t4[base + tid + NTHR   ];
        lt[tid + 2*NTHR ] = t4[base + tid + 2*NTHR ];
        __syncthreads();
        // Thread t owns rows 4t..4t+3 of the tile = float4s 3t..3t+2.
        float4 a0 = lp[3 * tid], a1 = lp[3 * tid + 1], a2 = lp[3 * tid + 2];
        float4 b0 = lt[3 * tid], b1 = lt[3 * tid + 1], b2 = lt[3 * tid + 2];
        acc += vmf_elem(a0.x, a0.y, a0.z, b0.x, b0.y, b0.z);
        acc += vmf_elem(a0.w, a1.x, a1.y, b0.w, b1.x, b1.y);
        acc += vmf_elem(a1.z, a1.w, a2.x, b1.z, b1.w, b2.x);
        acc += vmf_elem(a2.y, a2.z, a2.w, b2.y, b2.z, b2.w);
    }
    // Tail rows (< TILE_ROWS) by block 0, strided across its threads.
    if (blockIdx.x == 0) {
        for (int r = tid; r < nrem; r += NTHR) {
            long long i = nbase + r;
            acc += vmf_elem(pred[3 * i], pred[3 * i + 1], pred[3 * i + 2],
                            targ[3 * i], targ[3 * i + 1], targ[3 * i + 2]);
        }
    }

    // Wave shuffle reduction, then cross-wave via LDS.
    for (int off = 32; off > 0; off >>= 1)
        acc += __shfl_down(acc, off, 64);
    __shared__ float sdata[NTHR / 64];
    int lane = threadIdx.x & 63, wid = threadIdx.x >> 6;
    if (lane == 0) sdata[wid] = acc;
    __syncthreads();
    if (threadIdx.x == 0) {
        float s = 0.0f;
        #pragma unroll
        for (int w = 0; w < NTHR / 64; ++w) s += sdata[w];
        partial[blockIdx.x] = s;
    }
}

__global__ __launch_bounds__(NTHR) void vmf_final_kernel(
    const float* __restrict__ partial, float* __restrict__ out,
    int nblk, float invN) {
    float s = 0.0f;
    for (int i = threadIdx.x; i < nblk; i += NTHR) s += partial[i];
    for (int off = 32; off > 0; off >>= 1)
        s += __shfl_down(s, off, 64);
    __shared__ float sdata[NTHR / 64];
    int lane = threadIdx.x & 63, wid = threadIdx.x >> 6;
    if (lane == 0) sdata[wid] = s;
    __syncthreads();
    if (threadIdx.x == 0) {
        float tot = 0.0f;
        #pragma unroll
        for (int w = 0; w < NTHR / 64; ++w) tot += sdata[w];
        out[0] = tot * invN;
    }
}

extern "C" void kernel_launch(void* const* d_in, const int* in_sizes, int n_in,
                              void* d_out, int out_size, void* d_ws, size_t ws_size,
                              hipStream_t stream) {
    const float* pred = (const float*)d_in[0];
    const float* targ = (const float*)d_in[1];
    float* out = (float*)d_out;
    float* partial = (float*)d_ws;

    long long nrows = (long long)in_sizes[0] / 3;
    int ntiles = (int)(nrows / TILE_ROWS);
    int nrem   = (int)(nrows % TILE_ROWS);
    long long nbase = (long long)ntiles * TILE_ROWS;

    int blocks = ntiles < MAXBLK ? (ntiles > 0 ? ntiles : 1) : MAXBLK;

    vmf_partial_kernel<<<blocks, NTHR, 0, stream>>>(pred, targ, partial,
                                                    ntiles, nrem, nbase);
    vmf_final_kernel<<<1, NTHR, 0, stream>>>(partial, out, blocks,
                                             1.0f / (double)nrows);
}